// Round 3
// baseline (155.945 us; speedup 1.0000x reference)
//
#include <hip/hip_runtime.h>

#define NN  50000
#define DEG 32
#define DF  128
#define DO  256
#define FEAT4 (NN * DF / 4)   // 1,600,000 float4 groups

typedef __bf16 bf16x8 __attribute__((ext_vector_type(8)));
typedef float  f32x4  __attribute__((ext_vector_type(4)));

__device__ __forceinline__ unsigned short f2bf(float f) {
    unsigned u = __float_as_uint(f);
    u += 0x7FFF + ((u >> 16) & 1);     // round-to-nearest-even
    return (unsigned short)(u >> 16);
}
__device__ __forceinline__ float bf2f(unsigned short h) {
    return __uint_as_float(((unsigned)h) << 16);
}

// ---------------------------------------------------------------------------
// Convert: feat fp32 -> bf16 (vectorized), W fp32 [K][N] -> Wt bf16 [N][K].
// ---------------------------------------------------------------------------
__global__ __launch_bounds__(256) void convert_kernel(
    const float* __restrict__ feat, const float* __restrict__ W,
    unsigned short* __restrict__ featb, unsigned short* __restrict__ Wt)
{
    const int gid = blockIdx.x * 256 + threadIdx.x;
    if (gid < FEAT4) {
        const float4 v = ((const float4*)feat)[gid];
        ushort4 o;
        o.x = f2bf(v.x); o.y = f2bf(v.y); o.z = f2bf(v.z); o.w = f2bf(v.w);
        ((ushort4*)featb)[gid] = o;
    } else {
        const int t = gid - FEAT4;
        if (t < DO * DO) {
            const int n = t >> 8, k = t & 255;
            Wt[n * DO + k] = f2bf(W[k * DO + n]);   // write coalesced along k
        }
    }
}

// ---------------------------------------------------------------------------
// Fused kernel: one block per 64 nodes, BN = 256 (all of D_OUT).
// Phase 1: stage self-features (bf16) into LDS A-tile cols [0,128) and
//          gather+mean neighbors into cols [128,256). One barrier.
// Phase 2: barrier-free K-loop: A-frags from LDS, B-frags straight from
//          L2-resident Wt (128 KB), 16x16x32 bf16 MFMA, 4 waves x (64x64).
// LDS row stride 264 bf16 (528 B): bank shift 4/row -> worst 2-way on the
// MFMA ds_read_b128 (free per m136).
// ---------------------------------------------------------------------------
#define BM   64
#define LDA  264

__global__ __launch_bounds__(256) void fused_kernel(
    const unsigned short* __restrict__ featb,
    const int*            __restrict__ edges,
    const unsigned short* __restrict__ Wt,
    float*                __restrict__ out)
{
    __shared__ __align__(16) unsigned short Asw[BM * LDA];

    const int tid  = threadIdx.x;
    const int m0   = blockIdx.x * BM;
    const int wave = tid >> 6, lane = tid & 63;
    const int quad = lane >> 4, lr = lane & 15;
    const int wn   = wave * 64;          // each wave owns 64 output cols

    // ---- Phase 1a: self features -> A-tile cols [0,128) ----
    {
        const int row   = tid >> 2;      // 0..63
        const int cbase = tid & 3;       // 4 threads per row
        int node = m0 + row;
        if (node >= NN) node = NN - 1;
        #pragma unroll
        for (int p = 0; p < 4; ++p) {
            const int chunk = cbase + 4 * p;             // 0..15, 8 bf16 each
            const float4 v = *(const float4*)(featb + (size_t)node * DF + chunk * 8);
            *(float4*)(Asw + row * LDA + chunk * 8) = v;
        }
    }

    // ---- Phase 1b: gather + mean -> A-tile cols [128,256) ----
    {
        const int grp = tid >> 5;        // 0..7 (one node per 32-lane group)
        const int l   = tid & 31;        // float4-of-row within 128 feats
        #pragma unroll
        for (int p = 0; p < 8; ++p) {
            const int rloc = p * 8 + grp;               // 0..63
            int node = m0 + rloc;
            if (node >= NN) node = NN - 1;
            const int* e = edges + node * DEG;
            float a0 = 0.f, a1 = 0.f, a2 = 0.f, a3 = 0.f;
            #pragma unroll
            for (int d = 0; d < DEG; ++d) {
                const int idx = e[d];
                const ushort4 v = *(const ushort4*)(featb + (size_t)idx * DF + l * 4);
                a0 += bf2f(v.x); a1 += bf2f(v.y); a2 += bf2f(v.z); a3 += bf2f(v.w);
            }
            const float s = 1.0f / (float)DEG;
            ushort4 o;
            o.x = f2bf(a0 * s); o.y = f2bf(a1 * s);
            o.z = f2bf(a2 * s); o.w = f2bf(a3 * s);
            *(ushort4*)(Asw + rloc * LDA + DF + l * 4) = o;
        }
    }

    __syncthreads();

    // ---- Phase 2: barrier-free MFMA K-loop ----
    f32x4 acc[4][4] = {};
    #pragma unroll 2
    for (int kk = 0; kk < 256; kk += 32) {
        bf16x8 af[4], bfr[4];
        #pragma unroll
        for (int i = 0; i < 4; ++i) {
            af[i]  = *(const bf16x8*)(Asw + (i * 16 + lr) * LDA + kk + quad * 8);
            bfr[i] = *(const bf16x8*)(Wt + (size_t)(wn + i * 16 + lr) * DO + kk + quad * 8);
        }
        #pragma unroll
        for (int mi = 0; mi < 4; ++mi)
            #pragma unroll
            for (int ni = 0; ni < 4; ++ni)
                acc[mi][ni] = __builtin_amdgcn_mfma_f32_16x16x32_bf16(
                    af[mi], bfr[ni], acc[mi][ni], 0, 0, 0);
    }

    // ---- Epilogue: relu + guarded store. C/D: col=lane&15, row=quad*4+reg ----
    #pragma unroll
    for (int mi = 0; mi < 4; ++mi) {
        #pragma unroll
        for (int r = 0; r < 4; ++r) {
            const int row = m0 + mi * 16 + quad * 4 + r;
            if (row < NN) {
                #pragma unroll
                for (int ni = 0; ni < 4; ++ni) {
                    out[(size_t)row * DO + wn + ni * 16 + lr] =
                        fmaxf(acc[mi][ni][r], 0.f);
                }
            }
        }
    }
}

extern "C" void kernel_launch(void* const* d_in, const int* in_sizes, int n_in,
                              void* d_out, int out_size, void* d_ws, size_t ws_size,
                              hipStream_t stream)
{
    const float* feat  = (const float*)d_in[0];
    const int*   edges = (const int*)d_in[1];
    const float* W     = (const float*)d_in[2];
    float*       out   = (float*)d_out;

    unsigned short* featb = (unsigned short*)d_ws;        // 12.8 MB
    unsigned short* Wt    = featb + (size_t)NN * DF;      // 128 KB

    convert_kernel<<<(FEAT4 + DO * DO + 255) / 256, 256, 0, stream>>>(feat, W, featb, Wt);

    fused_kernel<<<(NN + BM - 1) / BM, 256, 0, stream>>>(featb, edges, Wt, out);
}